// Round 8
// baseline (1066.484 us; speedup 1.0000x reference)
//
#include <hip/hip_runtime.h>

typedef unsigned short u16;
typedef unsigned int u32;
typedef __bf16 bf16_t;
typedef bf16_t bf16x4 __attribute__((ext_vector_type(4)));
typedef bf16_t bf16x8 __attribute__((ext_vector_type(8)));
typedef float f32x4 __attribute__((ext_vector_type(4)));
typedef u16 u16x4 __attribute__((ext_vector_type(4)));
typedef u16 u16x8 __attribute__((ext_vector_type(8)));
typedef short s16x4 __attribute__((ext_vector_type(4)));

#define B_   4
#define L_   2048
#define HS_  2048
#define NH_  32
#define HD_  64
#define KK_  16
#define NM_  128
#define M_   (B_*L_)   // 8192

__device__ __forceinline__ u16 f2bf(float f) {
  unsigned u = __float_as_uint(f);
  u += 0x7FFFu + ((u >> 16) & 1u);   // RNE
  return (u16)(u >> 16);
}
__device__ __forceinline__ float bf2f(u16 u) {
  return __uint_as_float(((unsigned)u) << 16);
}
__device__ __forceinline__ s16x4 pk4(float a, float b, float c, float d) {
  bf16x4 v;
  v[0] = (__bf16)a; v[1] = (__bf16)b; v[2] = (__bf16)c; v[3] = (__bf16)d;
  return __builtin_bit_cast(s16x4, v);
}

// 16x16x16 bf16 MFMA (K=16): A lane=row l16 (k=quad*4+j), B lane=col l16,
// C row=quad*4+r col=l16.  C[i][j] = sum_k A[i][k]*B[j][k].
__device__ __forceinline__ f32x4 mfma16(s16x4 a, s16x4 b, f32x4 c) {
  return __builtin_amdgcn_mfma_f32_16x16x16bf16_1k(a, b, c, 0, 0, 0);
}

// DPP rotate-add within 16-lane rows
template <int CTRL>
__device__ __forceinline__ float dpp_add(float v) {
  int t = __builtin_amdgcn_update_dpp(0, __builtin_bit_cast(int, v), CTRL, 0xF, 0xF, true);
  return v + __builtin_bit_cast(float, t);
}
template <int CTRL>
__device__ __forceinline__ f32x4 dpp_add4(f32x4 v) {
  f32x4 r;
#pragma unroll
  for (int i = 0; i < 4; ++i) r[i] = dpp_add<CTRL>(v[i]);
  return r;
}
__device__ __forceinline__ f32x4 row_reduce16(f32x4 v) {
  v = dpp_add4<0x121>(v);  // row_ror:1
  v = dpp_add4<0x122>(v);  // row_ror:2
  v = dpp_add4<0x124>(v);  // row_ror:4
  v = dpp_add4<0x128>(v);  // row_ror:8
  return v;
}

// ---------------- cast f32 -> bf16 (8 elems/thread) ----------------
__global__ __launch_bounds__(256) void cast_f32_bf16(const float* __restrict__ in,
                                                     u16* __restrict__ out, int n) {
  int i = (blockIdx.x * 256 + threadIdx.x) * 8;
  if (i >= n) return;
  float4 a = *(const float4*)(in + i);
  float4 b = *(const float4*)(in + i + 4);
  u16x8 o;
  o[0]=f2bf(a.x); o[1]=f2bf(a.y); o[2]=f2bf(a.z); o[3]=f2bf(a.w);
  o[4]=f2bf(b.x); o[5]=f2bf(b.y); o[6]=f2bf(b.z); o[7]=f2bf(b.w);
  *(u16x8*)(out + i) = o;
}

// ---------------- bf16 MFMA GEMM, C = A(MxK) * Bt(NxK)^T (R3 reg-staged) ----------------
#define BM 128
#define BN 128
#define BK 32
#define LDT 40

template <bool BF16OUT>
__global__ __launch_bounds__(256) void gemm_nt(const u16* __restrict__ A,
                                               const u16* __restrict__ Bt,
                                               void* __restrict__ Cv,
                                               int M, int N, int K) {
  __shared__ u16 As[BM * LDT];
  __shared__ u16 Bs[BN * LDT];
  int tid  = threadIdx.x;
  int lane = tid & 63, wave = tid >> 6;
  int quad = lane >> 4, l16 = lane & 15;
  int bM = blockIdx.x * BM, bN = blockIdx.y * BN;
  int wM = (wave >> 1) * 64, wN = (wave & 1) * 64;
  int r0 = tid >> 2, c0 = (tid & 3) * 8;
  const u16* Ap = A + (size_t)bM * K;
  const u16* Bp = Bt + (size_t)bN * K;
  f32x4 acc[4][4] = {};
  u16x8 pa0 = *(const u16x8*)(Ap + (size_t)r0 * K + c0);
  u16x8 pa1 = *(const u16x8*)(Ap + (size_t)(r0 + 64) * K + c0);
  u16x8 pb0 = *(const u16x8*)(Bp + (size_t)r0 * K + c0);
  u16x8 pb1 = *(const u16x8*)(Bp + (size_t)(r0 + 64) * K + c0);
  int nk = K / BK;
  for (int kt = 0; kt < nk; ++kt) {
    *(u16x8*)&As[r0 * LDT + c0]        = pa0;
    *(u16x8*)&As[(r0 + 64) * LDT + c0] = pa1;
    *(u16x8*)&Bs[r0 * LDT + c0]        = pb0;
    *(u16x8*)&Bs[(r0 + 64) * LDT + c0] = pb1;
    __syncthreads();
    if (kt + 1 < nk) {
      int k0 = (kt + 1) * BK + c0;
      pa0 = *(const u16x8*)(Ap + (size_t)r0 * K + k0);
      pa1 = *(const u16x8*)(Ap + (size_t)(r0 + 64) * K + k0);
      pb0 = *(const u16x8*)(Bp + (size_t)r0 * K + k0);
      pb1 = *(const u16x8*)(Bp + (size_t)(r0 + 64) * K + k0);
    }
    bf16x8 af[4], bfr[4];
#pragma unroll
    for (int i = 0; i < 4; ++i) {
      u16x8 t = *(const u16x8*)&As[(wM + i * 16 + l16) * LDT + quad * 8];
      af[i] = __builtin_bit_cast(bf16x8, t);
    }
#pragma unroll
    for (int j = 0; j < 4; ++j) {
      u16x8 t = *(const u16x8*)&Bs[(wN + j * 16 + l16) * LDT + quad * 8];
      bfr[j] = __builtin_bit_cast(bf16x8, t);
    }
#pragma unroll
    for (int i = 0; i < 4; ++i) {
#pragma unroll
      for (int j = 0; j < 4; ++j)
        acc[i][j] = __builtin_amdgcn_mfma_f32_16x16x32_bf16(af[i], bfr[j], acc[i][j], 0, 0, 0);
    }
    __syncthreads();
  }
#pragma unroll
  for (int i = 0; i < 4; ++i) {
#pragma unroll
    for (int j = 0; j < 4; ++j) {
      int row = bM + wM + i * 16 + quad * 4;
      int col = bN + wN + j * 16 + l16;
      if (BF16OUT) {
        u16* cp = (u16*)Cv + (size_t)row * N + col;
#pragma unroll
        for (int r = 0; r < 4; ++r) cp[(size_t)r * N] = f2bf(acc[i][j][r]);
      } else {
        float* cp = (float*)Cv + (size_t)row * N + col;
#pragma unroll
        for (int r = 0; r < 4; ++r) cp[(size_t)r * N] = acc[i][j][r];
      }
    }
  }
}

// ---------------- lr projection: Sig[m,h] = sigmoid(hs_m . lrw_h + lrb_h)/HD ----------------
__global__ __launch_bounds__(256) void sig_kernel(const u16* __restrict__ hsb,
                                                  const u16* __restrict__ lrwb,
                                                  const float* __restrict__ lrb,
                                                  float* __restrict__ Sig) {
  __shared__ u16 Bs[32 * LDT];
  int tid = threadIdx.x;
  int lane = tid & 63, wave = tid >> 6;
  int quad = lane >> 4, l16 = lane & 15;
  int m0 = blockIdx.x * 64 + wave * 16;
  f32x4 acc0 = {}, acc1 = {};
  for (int kt = 0; kt < HS_ / BK; ++kt) {
    int k0 = kt * BK;
    if (tid < 128) {
      int r = tid >> 2, c8 = (tid & 3) * 8;
      *(u16x8*)&Bs[r * LDT + c8] = *(const u16x8*)(lrwb + (size_t)r * HS_ + k0 + c8);
    }
    __syncthreads();
    u16x8 ta = *(const u16x8*)(hsb + (size_t)(m0 + l16) * HS_ + k0 + quad * 8);
    u16x8 t0 = *(const u16x8*)&Bs[l16 * LDT + quad * 8];
    u16x8 t1 = *(const u16x8*)&Bs[(16 + l16) * LDT + quad * 8];
    bf16x8 af  = __builtin_bit_cast(bf16x8, ta);
    bf16x8 bf0 = __builtin_bit_cast(bf16x8, t0);
    bf16x8 bf1 = __builtin_bit_cast(bf16x8, t1);
    acc0 = __builtin_amdgcn_mfma_f32_16x16x32_bf16(af, bf0, acc0, 0, 0, 0);
    acc1 = __builtin_amdgcn_mfma_f32_16x16x32_bf16(af, bf1, acc1, 0, 0, 0);
    __syncthreads();
  }
#pragma unroll
  for (int j = 0; j < 2; ++j) {
    f32x4 a = j ? acc1 : acc0;
    int h = j * 16 + l16;
    float bias = lrb[h];
#pragma unroll
    for (int r = 0; r < 4; ++r) {
      int m = m0 + quad * 4 + r;
      float v = a[r] + bias;
      float s = (1.f / (1.f + expf(-v))) * (1.f / 64.f);
      Sig[(size_t)m * NH_ + h] = s;
    }
  }
}

// ---------------- TTT scan: 8 independent chains per 512-thread block ----------------
// Body identical to R7 (LDS-free, identity-MFMA transposes, verified 310us).
// Launch geometry change only: 8 waves/block -> 2 waves per SIMD, so the HW
// scheduler fills each wave's dependent-VALU stalls (~75% of cycles, R7 PMC)
// with the co-resident wave's instructions.  Chains are fully independent:
// no barriers, no LDS, no cross-wave state.  Chains in a block share b and
// read the same token rows (adjacent 128B head slices) -> L1/L2 locality.
__global__ __launch_bounds__(512, 2) void ttt_scan_wave(
    const u16* __restrict__ XQ, const u16* __restrict__ XK, const u16* __restrict__ XV,
    const float* __restrict__ Sig, const float* __restrict__ W1_0, const float* __restrict__ b1_0,
    const float* __restrict__ lnw, const float* __restrict__ lnb, const float* __restrict__ lti,
    float* __restrict__ Y) {
  int lane = threadIdx.x & 63;
  int wav  = threadIdx.x >> 6;
  int quad = lane >> 4, l16 = lane & 15;
  int bh = blockIdx.x * 8 + wav, b = bh >> 5, h = bh & 31;

  // identity B-frag: I[j=l16][k=quad*4+jj] = (l16 == quad*4+jj)
  s16x4 idB;
#pragma unroll
  for (int jj = 0; jj < 4; ++jj)
    idB[jj] = (l16 == quad * 4 + jj) ? (short)0x3F80 : (short)0;

  // W1 master: m2[c][a][r] = W1[d_in=c*16+quad*4+r][d_out=a*16+l16]
  f32x4 m2[4][4];
  {
    const float* wsrc = W1_0 + (size_t)h * 4096;
#pragma unroll
    for (int c = 0; c < 4; ++c)
#pragma unroll
      for (int a = 0; a < 4; ++a)
#pragma unroll
        for (int r = 0; r < 4; ++r)
          m2[c][a][r] = wsrc[(size_t)(c * 16 + quad * 4 + r) * 64 + a * 16 + l16];
  }

  f32x4 b1r, gam, bet;
#pragma unroll
  for (int a = 0; a < 4; ++a) {
    b1r[a] = b1_0[h * 64 + a * 16 + l16];
    gam[a] = lnw[h * 64 + a * 16 + l16];
    bet[a] = lnb[h * 64 + a * 16 + l16];
  }
  float tokL  = fmaxf(1.0f / (float)(l16 + 1) + lti[l16], 0.0f);
  float tok15 = fmaxf(1.0f / 16.0f + lti[15], 0.0f);

  size_t gb = ((size_t)(b * L_ + l16)) * HS_ + h * HD_ + quad * 4;
  const float* sigp = Sig + (size_t)(b * L_ + quad * 4) * NH_ + h;

  u16x4 cxk[4], cxq[4], cxv[4];
  f32x4 csig;
#pragma unroll
  for (int c = 0; c < 4; ++c) {
    cxk[c] = *(const u16x4*)(XK + gb + c * 16);
    cxq[c] = *(const u16x4*)(XQ + gb + c * 16);
    cxv[c] = *(const u16x4*)(XV + gb + c * 16);
  }
#pragma unroll
  for (int r = 0; r < 4; ++r) csig[r] = sigp[(size_t)r * NH_];

  for (int n = 0; n < NM_; ++n) {
    // ---- W1 B-frags from master (pure VALU) ----
    s16x4 fwB[4][4];
#pragma unroll
    for (int c = 0; c < 4; ++c)
#pragma unroll
      for (int a = 0; a < 4; ++a)
        fwB[c][a] = pk4(m2[c][a][0], m2[c][a][1], m2[c][a][2], m2[c][a][3]);

    // ---- fdiff = bf16(xv - xk) in A-frag layout (no LDS) ----
    s16x4 fdiff[4];
#pragma unroll
    for (int c = 0; c < 4; ++c) {
      float dv[4];
#pragma unroll
      for (int j = 0; j < 4; ++j) dv[j] = bf2f(cxv[c][j]) - bf2f(cxk[c][j]);
      fdiff[c] = pk4(dv[0], dv[1], dv[2], dv[3]);
    }

    s16x4 fxk[4], fxq[4];
#pragma unroll
    for (int c = 0; c < 4; ++c) {
      fxk[c] = __builtin_bit_cast(s16x4, cxk[c]);
      fxq[c] = __builtin_bit_cast(s16x4, cxq[c]);
    }
    f32x4 sigc = csig;

    // ---- prefetch step n+1 (latency spans the whole step) ----
    if (n + 1 < NM_) {
      size_t g = gb + (size_t)(n + 1) * KK_ * HS_;
#pragma unroll
      for (int c = 0; c < 4; ++c) {
        cxk[c] = *(const u16x4*)(XK + g + c * 16);
        cxq[c] = *(const u16x4*)(XQ + g + c * 16);
        cxv[c] = *(const u16x4*)(XV + g + c * 16);
      }
#pragma unroll
      for (int r = 0; r < 4; ++r)
        csig[r] = sigp[(size_t)((n + 1) * KK_ + r) * NH_];
    }

    // ---- z1 = xk@W1, zq = xq@W1, atT = xk@xq^T, + identity transposes ----
    f32x4 z1[4] = {}, zq4[4] = {}, atT = {};
    f32x4 ddC[4], xkC[4];
#pragma unroll
    for (int c = 0; c < 4; ++c) {
      f32x4 zz = {};
      atT    = mfma16(fxk[c], fxq[c], atT);
      xkC[c] = mfma16(fxk[c], idB, zz);
      ddC[c] = mfma16(fdiff[c], idB, zz);
#pragma unroll
      for (int a = 0; a < 4; ++a) {
        z1[a]  = mfma16(fxk[c], fwB[c][a], z1[a]);
        zq4[a] = mfma16(fxq[c], fwB[c][a], zq4[a]);
      }
    }

    // ---- fX = bf16(-tok15 * xk^T) in A-frag layout ----
    s16x4 fX[4];
#pragma unroll
    for (int c = 0; c < 4; ++c)
      fX[c] = pk4(-tok15 * xkC[c][0], -tok15 * xkC[c][1],
                  -tok15 * xkC[c][2], -tok15 * xkC[c][3]);

    // ---- fA[q=l16][j=quad*4+r] = -(j<=q) * tok_q * (1+Attn[q][j]) ----
    float cf[4];
#pragma unroll
    for (int r = 0; r < 4; ++r)
      cf[r] = (quad * 4 + r <= l16) ? -tokL * (1.0f + atT[r]) : 0.0f;
    s16x4 fA = pk4(cf[0], cf[1], cf[2], cf[3]);

    // ---- LN-bwd round 1: mean/var over d (DPP row reduce) ----
#pragma unroll
    for (int a = 0; a < 4; ++a)
#pragma unroll
      for (int r = 0; r < 4; ++r) z1[a][r] += b1r[a];
    f32x4 s1 = z1[0] + z1[1] + z1[2] + z1[3];
    f32x4 s2 = z1[0] * z1[0] + z1[1] * z1[1] + z1[2] * z1[2] + z1[3] * z1[3];
    s1 = row_reduce16(s1);
    s2 = row_reduce16(s2);
    f32x4 mu, rstd;
#pragma unroll
    for (int r = 0; r < 4; ++r) {
      mu[r] = s1[r] * (1.0f / 64.0f);
      float var = s2[r] * (1.0f / 64.0f) - mu[r] * mu[r];
      rstd[r] = 1.0f / sqrtf(var + 1e-6f);
    }

    // ---- gxh + round 2 (dd comes from ddC registers) ----
    f32x4 xh[4], gxh[4], t1v = {}, t2v = {};
#pragma unroll
    for (int a = 0; a < 4; ++a) {
#pragma unroll
      for (int r = 0; r < 4; ++r) {
        xh[a][r]  = (z1[a][r] - mu[r]) * rstd[r];
        gxh[a][r] = (gam[a] * xh[a][r] + bet[a] - ddC[a][r]) * gam[a];
      }
      t1v = t1v + gxh[a];
      t2v = t2v + gxh[a] * xh[a];
    }
    t1v = row_reduce16(t1v);
    t2v = row_reduce16(t2v);

    // ---- grad (sig folded) -> fG in-register; b1 partial sums ----
    s16x4 fG[4];
    float bs[4];
#pragma unroll
    for (int a = 0; a < 4; ++a) {
      float sg[4];
#pragma unroll
      for (int r = 0; r < 4; ++r) {
        float g = (64.0f * gxh[a][r] - t1v[r] - xh[a][r] * t2v[r]) * (rstd[r] * (1.0f / 64.0f));
        sg[r] = sigc[r] * g;
      }
      fG[a] = pk4(sg[0], sg[1], sg[2], sg[3]);
      bs[a] = sg[0] + sg[1] + sg[2] + sg[3];
    }
#pragma unroll
    for (int a = 0; a < 4; ++a) {
      bs[a] += __shfl_xor(bs[a], 16, 64);
      bs[a] += __shfl_xor(bs[a], 32, 64);
    }

    // ---- Zbar = zq + fA@fG + b1(old) ----
    f32x4 zb[4];
#pragma unroll
    for (int a = 0; a < 4; ++a) {
      zb[a] = mfma16(fA, fG[a], zq4[a]);
#pragma unroll
      for (int r = 0; r < 4; ++r) zb[a][r] += b1r[a];
    }
#pragma unroll
    for (int a = 0; a < 4; ++a) b1r[a] -= tok15 * bs[a];

    // ---- W1 update: m2[c][a] += fX[c] (x) fG[a] ----
#pragma unroll
    for (int c = 0; c < 4; ++c)
#pragma unroll
      for (int a = 0; a < 4; ++a)
        m2[c][a] = mfma16(fX[c], fG[a], m2[c][a]);

    // ---- Zbar LN (round 3) + store (residual added in postnorm) ----
    f32x4 w1s = zb[0] + zb[1] + zb[2] + zb[3];
    f32x4 w2s = zb[0] * zb[0] + zb[1] * zb[1] + zb[2] * zb[2] + zb[3] * zb[3];
    w1s = row_reduce16(w1s);
    w2s = row_reduce16(w2s);
#pragma unroll
    for (int r = 0; r < 4; ++r) {
      float mu2 = w1s[r] * (1.0f / 64.0f);
      float var2 = w2s[r] * (1.0f / 64.0f) - mu2 * mu2;
      float rstd2 = 1.0f / sqrtf(var2 + 1e-6f);
      float* yp = Y + ((size_t)(b * L_ + n * KK_ + quad * 4 + r)) * HS_ + h * HD_ + l16;
#pragma unroll
      for (int a = 0; a < 4; ++a)
        yp[a * 16] = gam[a] * ((zb[a][r] - mu2) * rstd2) + bet[a];
    }
  }
}

// ---------------- post-norm (adds xq residual, LN over HS=2048) -> bf16 ----------------
__global__ __launch_bounds__(256) void postnorm(const float* __restrict__ Yin,
                                                const u16* __restrict__ XQr,
                                                const float* __restrict__ w,
                                                const float* __restrict__ bb,
                                                u16* __restrict__ Yn) {
  __shared__ float red[8];
  int row = blockIdx.x, tid = threadIdx.x;
  const float* x = Yin + (size_t)row * HS_ + tid * 8;
  float4 v0 = *(const float4*)(x);
  float4 v1 = *(const float4*)(x + 4);
  u16x8 xqv = *(const u16x8*)(XQr + (size_t)row * HS_ + tid * 8);
  float vals[8] = {v0.x, v0.y, v0.z, v0.w, v1.x, v1.y, v1.z, v1.w};
#pragma unroll
  for (int t = 0; t < 8; ++t) vals[t] += bf2f(xqv[t]);
  float s = 0.f, ss = 0.f;
#pragma unroll
  for (int t = 0; t < 8; ++t) { s += vals[t]; ss += vals[t] * vals[t]; }
#pragma unroll
  for (int m = 32; m > 0; m >>= 1) { s += __shfl_xor(s, m, 64); ss += __shfl_xor(ss, m, 64); }
  int wave = tid >> 6, lane = tid & 63;
  if (lane == 0) { red[wave] = s; red[4 + wave] = ss; }
  __syncthreads();
  float S  = red[0] + red[1] + red[2] + red[3];
  float SS = red[4] + red[5] + red[6] + red[7];
  float mu = S * (1.f / 2048.f);
  float var = SS * (1.f / 2048.f) - mu * mu;
  float rstd = 1.f / sqrtf(var + 1e-6f);
  const float* wp = w + tid * 8;
  const float* bp = bb + tid * 8;
  u16x8 o;
#pragma unroll
  for (int t = 0; t < 8; ++t) o[t] = f2bf(wp[t] * ((vals[t] - mu) * rstd) + bp[t]);
  *(u16x8*)(Yn + (size_t)row * HS_ + tid * 8) = o;
}

extern "C" void kernel_launch(void* const* d_in, const int* in_sizes, int n_in,
                              void* d_out, int out_size, void* d_ws, size_t ws_size,
                              hipStream_t stream) {
  (void)in_sizes; (void)n_in; (void)out_size; (void)ws_size;
  const float* hidden = (const float*)d_in[0];
  const float* q_w = (const float*)d_in[2];
  const float* k_w = (const float*)d_in[3];
  const float* v_w = (const float*)d_in[4];
  const float* o_w = (const float*)d_in[5];
  const float* W1  = (const float*)d_in[6];
  const float* b1i = (const float*)d_in[7];
  const float* lnw = (const float*)d_in[8];
  const float* lnb = (const float*)d_in[9];
  const float* lrw = (const float*)d_in[10];
  const float* lrb = (const float*)d_in[11];
  const float* lti = (const float*)d_in[12];
  const float* pnw = (const float*)d_in[13];
  const float* pnb = (const float*)d_in[14];
  float* out = (float*)d_out;

  char* w = (char*)d_ws;
  u16* hsb  = (u16*)w;  w += (size_t)16777216 * 2;   // 32 MB; reused as Yn
  u16* wb   = (u16*)w;  w += (size_t)4194304 * 2;    // 8 MB (q/k/v/o reuse)
  u16* lrwb = (u16*)w;  w += (size_t)65536 * 2;
  u16* XQb  = (u16*)w;  w += (size_t)16777216 * 2;
  u16* XKb  = (u16*)w;  w += (size_t)16777216 * 2;
  u16* XVb  = (u16*)w;  w += (size_t)16777216 * 2;
  float* Sg = (float*)w; w += (size_t)M_ * NH_ * 4;
  u16* Yn = hsb;

  cast_f32_bf16<<<8192, 256, 0, stream>>>(hidden, hsb, 16777216);
  cast_f32_bf16<<<32, 256, 0, stream>>>(lrw, lrwb, 65536);

  sig_kernel<<<128, 256, 0, stream>>>(hsb, lrwb, lrb, Sg);

  dim3 gg(M_ / BM, HS_ / BN);
  cast_f32_bf16<<<2048, 256, 0, stream>>>(q_w, wb, 4194304);
  gemm_nt<true><<<gg, 256, 0, stream>>>(hsb, wb, XQb, M_, HS_, HS_);
  cast_f32_bf16<<<2048, 256, 0, stream>>>(k_w, wb, 4194304);
  gemm_nt<true><<<gg, 256, 0, stream>>>(hsb, wb, XKb, M_, HS_, HS_);
  cast_f32_bf16<<<2048, 256, 0, stream>>>(v_w, wb, 4194304);
  gemm_nt<true><<<gg, 256, 0, stream>>>(hsb, wb, XVb, M_, HS_, HS_);

  ttt_scan_wave<<<16, 512, 0, stream>>>(XQb, XKb, XVb, Sg, W1, b1i, lnw, lnb, lti, out);

  postnorm<<<8192, 256, 0, stream>>>(out, XQb, pnw, pnb, Yn);

  cast_f32_bf16<<<2048, 256, 0, stream>>>(o_w, wb, 4194304);
  gemm_nt<false><<<gg, 256, 0, stream>>>(Yn, wb, out, M_, HS_, HS_);
}

// Round 9
// 892.959 us; speedup vs baseline: 1.1943x; 1.1943x over previous
//
#include <hip/hip_runtime.h>

typedef unsigned short u16;
typedef unsigned int u32;
typedef __bf16 bf16_t;
typedef bf16_t bf16x4 __attribute__((ext_vector_type(4)));
typedef bf16_t bf16x8 __attribute__((ext_vector_type(8)));
typedef float f32x4 __attribute__((ext_vector_type(4)));
typedef u16 u16x4 __attribute__((ext_vector_type(4)));
typedef u16 u16x8 __attribute__((ext_vector_type(8)));
typedef short s16x4 __attribute__((ext_vector_type(4)));

#define B_   4
#define L_   2048
#define HS_  2048
#define NH_  32
#define HD_  64
#define KK_  16
#define NM_  128
#define M_   (B_*L_)   // 8192

__device__ __forceinline__ u16 f2bf(float f) {
  unsigned u = __float_as_uint(f);
  u += 0x7FFFu + ((u >> 16) & 1u);   // RNE
  return (u16)(u >> 16);
}
__device__ __forceinline__ float bf2f(u16 u) {
  return __uint_as_float(((unsigned)u) << 16);
}
__device__ __forceinline__ s16x4 pk4(float a, float b, float c, float d) {
  bf16x4 v;
  v[0] = (__bf16)a; v[1] = (__bf16)b; v[2] = (__bf16)c; v[3] = (__bf16)d;
  return __builtin_bit_cast(s16x4, v);
}

// 16x16x16 bf16 MFMA (K=16): A lane=row l16 (k=quad*4+j), B lane=col l16,
// C row=quad*4+r col=l16.  C[i][j] = sum_k A[i][k]*B[j][k].
__device__ __forceinline__ f32x4 mfma16(s16x4 a, s16x4 b, f32x4 c) {
  return __builtin_amdgcn_mfma_f32_16x16x16bf16_1k(a, b, c, 0, 0, 0);
}

// DPP rotate-add within 16-lane rows
template <int CTRL>
__device__ __forceinline__ float dpp_add(float v) {
  int t = __builtin_amdgcn_update_dpp(0, __builtin_bit_cast(int, v), CTRL, 0xF, 0xF, true);
  return v + __builtin_bit_cast(float, t);
}
template <int CTRL>
__device__ __forceinline__ f32x4 dpp_add4(f32x4 v) {
  f32x4 r;
#pragma unroll
  for (int i = 0; i < 4; ++i) r[i] = dpp_add<CTRL>(v[i]);
  return r;
}
__device__ __forceinline__ f32x4 row_reduce16(f32x4 v) {
  v = dpp_add4<0x121>(v);  // row_ror:1
  v = dpp_add4<0x122>(v);  // row_ror:2
  v = dpp_add4<0x124>(v);  // row_ror:4
  v = dpp_add4<0x128>(v);  // row_ror:8
  return v;
}

// ---------------- cast f32 -> bf16 (8 elems/thread) ----------------
__global__ __launch_bounds__(256) void cast_f32_bf16(const float* __restrict__ in,
                                                     u16* __restrict__ out, int n) {
  int i = (blockIdx.x * 256 + threadIdx.x) * 8;
  if (i >= n) return;
  float4 a = *(const float4*)(in + i);
  float4 b = *(const float4*)(in + i + 4);
  u16x8 o;
  o[0]=f2bf(a.x); o[1]=f2bf(a.y); o[2]=f2bf(a.z); o[3]=f2bf(a.w);
  o[4]=f2bf(b.x); o[5]=f2bf(b.y); o[6]=f2bf(b.z); o[7]=f2bf(b.w);
  *(u16x8*)(out + i) = o;
}

// ---------------- bf16 MFMA GEMM, C = A(MxK) * Bt(NxK)^T (R3 reg-staged) ----------------
#define BM 128
#define BN 128
#define BK 32
#define LDT 40

template <bool BF16OUT>
__global__ __launch_bounds__(256) void gemm_nt(const u16* __restrict__ A,
                                               const u16* __restrict__ Bt,
                                               void* __restrict__ Cv,
                                               int M, int N, int K) {
  __shared__ u16 As[BM * LDT];
  __shared__ u16 Bs[BN * LDT];
  int tid  = threadIdx.x;
  int lane = tid & 63, wave = tid >> 6;
  int quad = lane >> 4, l16 = lane & 15;
  int bM = blockIdx.x * BM, bN = blockIdx.y * BN;
  int wM = (wave >> 1) * 64, wN = (wave & 1) * 64;
  int r0 = tid >> 2, c0 = (tid & 3) * 8;
  const u16* Ap = A + (size_t)bM * K;
  const u16* Bp = Bt + (size_t)bN * K;
  f32x4 acc[4][4] = {};
  u16x8 pa0 = *(const u16x8*)(Ap + (size_t)r0 * K + c0);
  u16x8 pa1 = *(const u16x8*)(Ap + (size_t)(r0 + 64) * K + c0);
  u16x8 pb0 = *(const u16x8*)(Bp + (size_t)r0 * K + c0);
  u16x8 pb1 = *(const u16x8*)(Bp + (size_t)(r0 + 64) * K + c0);
  int nk = K / BK;
  for (int kt = 0; kt < nk; ++kt) {
    *(u16x8*)&As[r0 * LDT + c0]        = pa0;
    *(u16x8*)&As[(r0 + 64) * LDT + c0] = pa1;
    *(u16x8*)&Bs[r0 * LDT + c0]        = pb0;
    *(u16x8*)&Bs[(r0 + 64) * LDT + c0] = pb1;
    __syncthreads();
    if (kt + 1 < nk) {
      int k0 = (kt + 1) * BK + c0;
      pa0 = *(const u16x8*)(Ap + (size_t)r0 * K + k0);
      pa1 = *(const u16x8*)(Ap + (size_t)(r0 + 64) * K + k0);
      pb0 = *(const u16x8*)(Bp + (size_t)r0 * K + k0);
      pb1 = *(const u16x8*)(Bp + (size_t)(r0 + 64) * K + k0);
    }
    bf16x8 af[4], bfr[4];
#pragma unroll
    for (int i = 0; i < 4; ++i) {
      u16x8 t = *(const u16x8*)&As[(wM + i * 16 + l16) * LDT + quad * 8];
      af[i] = __builtin_bit_cast(bf16x8, t);
    }
#pragma unroll
    for (int j = 0; j < 4; ++j) {
      u16x8 t = *(const u16x8*)&Bs[(wN + j * 16 + l16) * LDT + quad * 8];
      bfr[j] = __builtin_bit_cast(bf16x8, t);
    }
#pragma unroll
    for (int i = 0; i < 4; ++i) {
#pragma unroll
      for (int j = 0; j < 4; ++j)
        acc[i][j] = __builtin_amdgcn_mfma_f32_16x16x32_bf16(af[i], bfr[j], acc[i][j], 0, 0, 0);
    }
    __syncthreads();
  }
#pragma unroll
  for (int i = 0; i < 4; ++i) {
#pragma unroll
    for (int j = 0; j < 4; ++j) {
      int row = bM + wM + i * 16 + quad * 4;
      int col = bN + wN + j * 16 + l16;
      if (BF16OUT) {
        u16* cp = (u16*)Cv + (size_t)row * N + col;
#pragma unroll
        for (int r = 0; r < 4; ++r) cp[(size_t)r * N] = f2bf(acc[i][j][r]);
      } else {
        float* cp = (float*)Cv + (size_t)row * N + col;
#pragma unroll
        for (int r = 0; r < 4; ++r) cp[(size_t)r * N] = acc[i][j][r];
      }
    }
  }
}

// ---------------- fused QKV GEMM: stage A once, 3 B-panels ----------------
// Xw = A(8192x2048) * Bw(2048x2048)^T for w in {q,k,v}.  BM=128, BN=64, BK=32.
// 4 waves; wave w owns rows wM=w*32 (2 A-frags), all 64 cols (4 B-frags/weight).
// acc[3][2][4] = 96 VGPR.  Staging/FLOP is 2.4x lower than separate GEMMs.
__global__ __launch_bounds__(256) void gemm_qkv(const u16* __restrict__ A,
                                                const u16* __restrict__ Bq,
                                                const u16* __restrict__ Bk,
                                                const u16* __restrict__ Bv,
                                                u16* __restrict__ Xq,
                                                u16* __restrict__ Xk,
                                                u16* __restrict__ Xv) {
  const int K = HS_, N = HS_;
  __shared__ u16 As[128 * LDT];
  __shared__ u16 Bs[3][64 * LDT];
  int tid  = threadIdx.x;
  int lane = tid & 63, wave = tid >> 6;
  int quad = lane >> 4, l16 = lane & 15;
  int bM = blockIdx.x * 128, bN = blockIdx.y * 64;
  int wM = wave * 32;
  int r0a = tid >> 1, c0a = (tid & 1) * 16;   // A: 2 chunks (16 u16) per thread
  int r0b = tid >> 2, c0b = (tid & 3) * 8;    // B: 1 chunk per weight per thread
  const u16* Ap = A + (size_t)(bM + r0a) * K + c0a;
  const u16* Bp[3] = {Bq + (size_t)(bN + r0b) * K + c0b,
                      Bk + (size_t)(bN + r0b) * K + c0b,
                      Bv + (size_t)(bN + r0b) * K + c0b};
  f32x4 acc[3][2][4] = {};
  u16x8 pa0 = *(const u16x8*)(Ap);
  u16x8 pa1 = *(const u16x8*)(Ap + 8);
  u16x8 pb[3];
#pragma unroll
  for (int wgt = 0; wgt < 3; ++wgt) pb[wgt] = *(const u16x8*)(Bp[wgt]);
  int nk = K / BK;
  for (int kt = 0; kt < nk; ++kt) {
    *(u16x8*)&As[r0a * LDT + c0a]     = pa0;
    *(u16x8*)&As[r0a * LDT + c0a + 8] = pa1;
#pragma unroll
    for (int wgt = 0; wgt < 3; ++wgt)
      *(u16x8*)&Bs[wgt][r0b * LDT + c0b] = pb[wgt];
    __syncthreads();
    if (kt + 1 < nk) {
      int k0 = (kt + 1) * BK;
      pa0 = *(const u16x8*)(Ap + k0);
      pa1 = *(const u16x8*)(Ap + k0 + 8);
#pragma unroll
      for (int wgt = 0; wgt < 3; ++wgt) pb[wgt] = *(const u16x8*)(Bp[wgt] + k0);
    }
    bf16x8 af[2];
#pragma unroll
    for (int i = 0; i < 2; ++i) {
      u16x8 t = *(const u16x8*)&As[(wM + i * 16 + l16) * LDT + quad * 8];
      af[i] = __builtin_bit_cast(bf16x8, t);
    }
#pragma unroll
    for (int wgt = 0; wgt < 3; ++wgt) {
#pragma unroll
      for (int j = 0; j < 4; ++j) {
        u16x8 t = *(const u16x8*)&Bs[wgt][(j * 16 + l16) * LDT + quad * 8];
        bf16x8 bfr = __builtin_bit_cast(bf16x8, t);
#pragma unroll
        for (int i = 0; i < 2; ++i)
          acc[wgt][i][j] = __builtin_amdgcn_mfma_f32_16x16x32_bf16(af[i], bfr, acc[wgt][i][j], 0, 0, 0);
      }
    }
    __syncthreads();
  }
  u16* outs[3] = {Xq, Xk, Xv};
#pragma unroll
  for (int wgt = 0; wgt < 3; ++wgt) {
#pragma unroll
    for (int i = 0; i < 2; ++i) {
#pragma unroll
      for (int j = 0; j < 4; ++j) {
        int row = bM + wM + i * 16 + quad * 4;
        int col = bN + j * 16 + l16;
        u16* cp = outs[wgt] + (size_t)row * N + col;
#pragma unroll
        for (int r = 0; r < 4; ++r) cp[(size_t)r * N] = f2bf(acc[wgt][i][j][r]);
      }
    }
  }
}

// ---------------- lr projection: Sig[m,h] = sigmoid(hs_m . lrw_h + lrb_h)/HD ----------------
__global__ __launch_bounds__(256) void sig_kernel(const u16* __restrict__ hsb,
                                                  const u16* __restrict__ lrwb,
                                                  const float* __restrict__ lrb,
                                                  float* __restrict__ Sig) {
  __shared__ u16 Bs[32 * LDT];
  int tid = threadIdx.x;
  int lane = tid & 63, wave = tid >> 6;
  int quad = lane >> 4, l16 = lane & 15;
  int m0 = blockIdx.x * 64 + wave * 16;
  f32x4 acc0 = {}, acc1 = {};
  for (int kt = 0; kt < HS_ / BK; ++kt) {
    int k0 = kt * BK;
    if (tid < 128) {
      int r = tid >> 2, c8 = (tid & 3) * 8;
      *(u16x8*)&Bs[r * LDT + c8] = *(const u16x8*)(lrwb + (size_t)r * HS_ + k0 + c8);
    }
    __syncthreads();
    u16x8 ta = *(const u16x8*)(hsb + (size_t)(m0 + l16) * HS_ + k0 + quad * 8);
    u16x8 t0 = *(const u16x8*)&Bs[l16 * LDT + quad * 8];
    u16x8 t1 = *(const u16x8*)&Bs[(16 + l16) * LDT + quad * 8];
    bf16x8 af  = __builtin_bit_cast(bf16x8, ta);
    bf16x8 bf0 = __builtin_bit_cast(bf16x8, t0);
    bf16x8 bf1 = __builtin_bit_cast(bf16x8, t1);
    acc0 = __builtin_amdgcn_mfma_f32_16x16x32_bf16(af, bf0, acc0, 0, 0, 0);
    acc1 = __builtin_amdgcn_mfma_f32_16x16x32_bf16(af, bf1, acc1, 0, 0, 0);
    __syncthreads();
  }
#pragma unroll
  for (int j = 0; j < 2; ++j) {
    f32x4 a = j ? acc1 : acc0;
    int h = j * 16 + l16;
    float bias = lrb[h];
#pragma unroll
    for (int r = 0; r < 4; ++r) {
      int m = m0 + quad * 4 + r;
      float v = a[r] + bias;
      float s = (1.f / (1.f + expf(-v))) * (1.f / 64.f);
      Sig[(size_t)m * NH_ + h] = s;
    }
  }
}

// ---------------- single-wave TTT scan (R7-verified: LDS-free, 310us) ----------------
__global__ __launch_bounds__(64, 1) void ttt_scan_wave(
    const u16* __restrict__ XQ, const u16* __restrict__ XK, const u16* __restrict__ XV,
    const float* __restrict__ Sig, const float* __restrict__ W1_0, const float* __restrict__ b1_0,
    const float* __restrict__ lnw, const float* __restrict__ lnb, const float* __restrict__ lti,
    float* __restrict__ Y) {
  int lane = threadIdx.x;
  int quad = lane >> 4, l16 = lane & 15;
  int bh = blockIdx.x, b = bh >> 5, h = bh & 31;

  // identity B-frag: I[j=l16][k=quad*4+jj] = (l16 == quad*4+jj)
  s16x4 idB;
#pragma unroll
  for (int jj = 0; jj < 4; ++jj)
    idB[jj] = (l16 == quad * 4 + jj) ? (short)0x3F80 : (short)0;

  // W1 master: m2[c][a][r] = W1[d_in=c*16+quad*4+r][d_out=a*16+l16]
  f32x4 m2[4][4];
  {
    const float* wsrc = W1_0 + (size_t)h * 4096;
#pragma unroll
    for (int c = 0; c < 4; ++c)
#pragma unroll
      for (int a = 0; a < 4; ++a)
#pragma unroll
        for (int r = 0; r < 4; ++r)
          m2[c][a][r] = wsrc[(size_t)(c * 16 + quad * 4 + r) * 64 + a * 16 + l16];
  }

  f32x4 b1r, gam, bet;
#pragma unroll
  for (int a = 0; a < 4; ++a) {
    b1r[a] = b1_0[h * 64 + a * 16 + l16];
    gam[a] = lnw[h * 64 + a * 16 + l16];
    bet[a] = lnb[h * 64 + a * 16 + l16];
  }
  float tokL  = fmaxf(1.0f / (float)(l16 + 1) + lti[l16], 0.0f);
  float tok15 = fmaxf(1.0f / 16.0f + lti[15], 0.0f);

  size_t gb = ((size_t)(b * L_ + l16)) * HS_ + h * HD_ + quad * 4;
  const float* sigp = Sig + (size_t)(b * L_ + quad * 4) * NH_ + h;

  u16x4 cxk[4], cxq[4], cxv[4];
  f32x4 csig;
#pragma unroll
  for (int c = 0; c < 4; ++c) {
    cxk[c] = *(const u16x4*)(XK + gb + c * 16);
    cxq[c] = *(const u16x4*)(XQ + gb + c * 16);
    cxv[c] = *(const u16x4*)(XV + gb + c * 16);
  }
#pragma unroll
  for (int r = 0; r < 4; ++r) csig[r] = sigp[(size_t)r * NH_];

  for (int n = 0; n < NM_; ++n) {
    // ---- W1 B-frags from master (pure VALU) ----
    s16x4 fwB[4][4];
#pragma unroll
    for (int c = 0; c < 4; ++c)
#pragma unroll
      for (int a = 0; a < 4; ++a)
        fwB[c][a] = pk4(m2[c][a][0], m2[c][a][1], m2[c][a][2], m2[c][a][3]);

    // ---- fdiff = bf16(xv - xk) in A-frag layout (no LDS) ----
    s16x4 fdiff[4];
#pragma unroll
    for (int c = 0; c < 4; ++c) {
      float dv[4];
#pragma unroll
      for (int j = 0; j < 4; ++j) dv[j] = bf2f(cxv[c][j]) - bf2f(cxk[c][j]);
      fdiff[c] = pk4(dv[0], dv[1], dv[2], dv[3]);
    }

    s16x4 fxk[4], fxq[4];
#pragma unroll
    for (int c = 0; c < 4; ++c) {
      fxk[c] = __builtin_bit_cast(s16x4, cxk[c]);
      fxq[c] = __builtin_bit_cast(s16x4, cxq[c]);
    }
    f32x4 sigc = csig;

    // ---- prefetch step n+1 (latency spans the whole step) ----
    if (n + 1 < NM_) {
      size_t g = gb + (size_t)(n + 1) * KK_ * HS_;
#pragma unroll
      for (int c = 0; c < 4; ++c) {
        cxk[c] = *(const u16x4*)(XK + g + c * 16);
        cxq[c] = *(const u16x4*)(XQ + g + c * 16);
        cxv[c] = *(const u16x4*)(XV + g + c * 16);
      }
#pragma unroll
      for (int r = 0; r < 4; ++r)
        csig[r] = sigp[(size_t)((n + 1) * KK_ + r) * NH_];
    }

    // ---- z1 = xk@W1, zq = xq@W1, atT = xk@xq^T, + identity transposes ----
    f32x4 z1[4] = {}, zq4[4] = {}, atT = {};
    f32x4 ddC[4], xkC[4];
#pragma unroll
    for (int c = 0; c < 4; ++c) {
      f32x4 zz = {};
      atT    = mfma16(fxk[c], fxq[c], atT);
      xkC[c] = mfma16(fxk[c], idB, zz);
      ddC[c] = mfma16(fdiff[c], idB, zz);
#pragma unroll
      for (int a = 0; a < 4; ++a) {
        z1[a]  = mfma16(fxk[c], fwB[c][a], z1[a]);
        zq4[a] = mfma16(fxq[c], fwB[c][a], zq4[a]);
      }
    }

    // ---- fX = bf16(-tok15 * xk^T) in A-frag layout ----
    s16x4 fX[4];
#pragma unroll
    for (int c = 0; c < 4; ++c)
      fX[c] = pk4(-tok15 * xkC[c][0], -tok15 * xkC[c][1],
                  -tok15 * xkC[c][2], -tok15 * xkC[c][3]);

    // ---- fA[q=l16][j=quad*4+r] = -(j<=q) * tok_q * (1+Attn[q][j]) ----
    float cf[4];
#pragma unroll
    for (int r = 0; r < 4; ++r)
      cf[r] = (quad * 4 + r <= l16) ? -tokL * (1.0f + atT[r]) : 0.0f;
    s16x4 fA = pk4(cf[0], cf[1], cf[2], cf[3]);

    // ---- LN-bwd round 1: mean/var over d (DPP row reduce) ----
#pragma unroll
    for (int a = 0; a < 4; ++a)
#pragma unroll
      for (int r = 0; r < 4; ++r) z1[a][r] += b1r[a];
    f32x4 s1 = z1[0] + z1[1] + z1[2] + z1[3];
    f32x4 s2 = z1[0] * z1[0] + z1[1] * z1[1] + z1[2] * z1[2] + z1[3] * z1[3];
    s1 = row_reduce16(s1);
    s2 = row_reduce16(s2);
    f32x4 mu, rstd;
#pragma unroll
    for (int r = 0; r < 4; ++r) {
      mu[r] = s1[r] * (1.0f / 64.0f);
      float var = s2[r] * (1.0f / 64.0f) - mu[r] * mu[r];
      rstd[r] = 1.0f / sqrtf(var + 1e-6f);
    }

    // ---- gxh + round 2 (dd comes from ddC registers) ----
    f32x4 xh[4], gxh[4], t1v = {}, t2v = {};
#pragma unroll
    for (int a = 0; a < 4; ++a) {
#pragma unroll
      for (int r = 0; r < 4; ++r) {
        xh[a][r]  = (z1[a][r] - mu[r]) * rstd[r];
        gxh[a][r] = (gam[a] * xh[a][r] + bet[a] - ddC[a][r]) * gam[a];
      }
      t1v = t1v + gxh[a];
      t2v = t2v + gxh[a] * xh[a];
    }
    t1v = row_reduce16(t1v);
    t2v = row_reduce16(t2v);

    // ---- grad (sig folded) -> fG in-register; b1 partial sums ----
    s16x4 fG[4];
    float bs[4];
#pragma unroll
    for (int a = 0; a < 4; ++a) {
      float sg[4];
#pragma unroll
      for (int r = 0; r < 4; ++r) {
        float g = (64.0f * gxh[a][r] - t1v[r] - xh[a][r] * t2v[r]) * (rstd[r] * (1.0f / 64.0f));
        sg[r] = sigc[r] * g;
      }
      fG[a] = pk4(sg[0], sg[1], sg[2], sg[3]);
      bs[a] = sg[0] + sg[1] + sg[2] + sg[3];
    }
#pragma unroll
    for (int a = 0; a < 4; ++a) {
      bs[a] += __shfl_xor(bs[a], 16, 64);
      bs[a] += __shfl_xor(bs[a], 32, 64);
    }

    // ---- Zbar = zq + fA@fG + b1(old) ----
    f32x4 zb[4];
#pragma unroll
    for (int a = 0; a < 4; ++a) {
      zb[a] = mfma16(fA, fG[a], zq4[a]);
#pragma unroll
      for (int r = 0; r < 4; ++r) zb[a][r] += b1r[a];
    }
#pragma unroll
    for (int a = 0; a < 4; ++a) b1r[a] -= tok15 * bs[a];

    // ---- W1 update: m2[c][a] += fX[c] (x) fG[a] ----
#pragma unroll
    for (int c = 0; c < 4; ++c)
#pragma unroll
      for (int a = 0; a < 4; ++a)
        m2[c][a] = mfma16(fX[c], fG[a], m2[c][a]);

    // ---- Zbar LN (round 3) + store (residual added in postnorm) ----
    f32x4 w1s = zb[0] + zb[1] + zb[2] + zb[3];
    f32x4 w2s = zb[0] * zb[0] + zb[1] * zb[1] + zb[2] * zb[2] + zb[3] * zb[3];
    w1s = row_reduce16(w1s);
    w2s = row_reduce16(w2s);
#pragma unroll
    for (int r = 0; r < 4; ++r) {
      float mu2 = w1s[r] * (1.0f / 64.0f);
      float var2 = w2s[r] * (1.0f / 64.0f) - mu2 * mu2;
      float rstd2 = 1.0f / sqrtf(var2 + 1e-6f);
      float* yp = Y + ((size_t)(b * L_ + n * KK_ + quad * 4 + r)) * HS_ + h * HD_ + l16;
#pragma unroll
      for (int a = 0; a < 4; ++a)
        yp[a * 16] = gam[a] * ((zb[a][r] - mu2) * rstd2) + bet[a];
    }
  }
}

// ---------------- post-norm (adds xq residual, LN over HS=2048) -> bf16 ----------------
__global__ __launch_bounds__(256) void postnorm(const float* __restrict__ Yin,
                                                const u16* __restrict__ XQr,
                                                const float* __restrict__ w,
                                                const float* __restrict__ bb,
                                                u16* __restrict__ Yn) {
  __shared__ float red[8];
  int row = blockIdx.x, tid = threadIdx.x;
  const float* x = Yin + (size_t)row * HS_ + tid * 8;
  float4 v0 = *(const float4*)(x);
  float4 v1 = *(const float4*)(x + 4);
  u16x8 xqv = *(const u16x8*)(XQr + (size_t)row * HS_ + tid * 8);
  float vals[8] = {v0.x, v0.y, v0.z, v0.w, v1.x, v1.y, v1.z, v1.w};
#pragma unroll
  for (int t = 0; t < 8; ++t) vals[t] += bf2f(xqv[t]);
  float s = 0.f, ss = 0.f;
#pragma unroll
  for (int t = 0; t < 8; ++t) { s += vals[t]; ss += vals[t] * vals[t]; }
#pragma unroll
  for (int m = 32; m > 0; m >>= 1) { s += __shfl_xor(s, m, 64); ss += __shfl_xor(ss, m, 64); }
  int wave = tid >> 6, lane = tid & 63;
  if (lane == 0) { red[wave] = s; red[4 + wave] = ss; }
  __syncthreads();
  float S  = red[0] + red[1] + red[2] + red[3];
  float SS = red[4] + red[5] + red[6] + red[7];
  float mu = S * (1.f / 2048.f);
  float var = SS * (1.f / 2048.f) - mu * mu;
  float rstd = 1.f / sqrtf(var + 1e-6f);
  const float* wp = w + tid * 8;
  const float* bp = bb + tid * 8;
  u16x8 o;
#pragma unroll
  for (int t = 0; t < 8; ++t) o[t] = f2bf(wp[t] * ((vals[t] - mu) * rstd) + bp[t]);
  *(u16x8*)(Yn + (size_t)row * HS_ + tid * 8) = o;
}

extern "C" void kernel_launch(void* const* d_in, const int* in_sizes, int n_in,
                              void* d_out, int out_size, void* d_ws, size_t ws_size,
                              hipStream_t stream) {
  (void)in_sizes; (void)n_in; (void)out_size; (void)ws_size;
  const float* hidden = (const float*)d_in[0];
  const float* q_w = (const float*)d_in[2];
  const float* k_w = (const float*)d_in[3];
  const float* v_w = (const float*)d_in[4];
  const float* o_w = (const float*)d_in[5];
  const float* W1  = (const float*)d_in[6];
  const float* b1i = (const float*)d_in[7];
  const float* lnw = (const float*)d_in[8];
  const float* lnb = (const float*)d_in[9];
  const float* lrw = (const float*)d_in[10];
  const float* lrb = (const float*)d_in[11];
  const float* lti = (const float*)d_in[12];
  const float* pnw = (const float*)d_in[13];
  const float* pnb = (const float*)d_in[14];
  float* out = (float*)d_out;

  char* w = (char*)d_ws;
  u16* hsb  = (u16*)w;  w += (size_t)16777216 * 2;   // 32 MB; reused as Yn
  u16* wbq  = (u16*)w;  w += (size_t)4194304 * 2;    // 8 MB
  u16* wbk  = (u16*)w;  w += (size_t)4194304 * 2;    // 8 MB
  u16* wbv  = (u16*)w;  w += (size_t)4194304 * 2;    // 8 MB (reused for o_w)
  u16* lrwb = (u16*)w;  w += (size_t)65536 * 2;
  u16* XQb  = (u16*)w;  w += (size_t)16777216 * 2;
  u16* XKb  = (u16*)w;  w += (size_t)16777216 * 2;
  u16* XVb  = (u16*)w;  w += (size_t)16777216 * 2;
  float* Sg = (float*)w; w += (size_t)M_ * NH_ * 4;
  u16* Yn = hsb;

  cast_f32_bf16<<<8192, 256, 0, stream>>>(hidden, hsb, 16777216);
  cast_f32_bf16<<<32, 256, 0, stream>>>(lrw, lrwb, 65536);

  sig_kernel<<<128, 256, 0, stream>>>(hsb, lrwb, lrb, Sg);

  cast_f32_bf16<<<2048, 256, 0, stream>>>(q_w, wbq, 4194304);
  cast_f32_bf16<<<2048, 256, 0, stream>>>(k_w, wbk, 4194304);
  cast_f32_bf16<<<2048, 256, 0, stream>>>(v_w, wbv, 4194304);
  dim3 gq(M_ / 128, HS_ / 64);
  gemm_qkv<<<gq, 256, 0, stream>>>(hsb, wbq, wbk, wbv, XQb, XKb, XVb);

  ttt_scan_wave<<<128, 64, 0, stream>>>(XQb, XKb, XVb, Sg, W1, b1i, lnw, lnb, lti, out);

  postnorm<<<8192, 256, 0, stream>>>(out, XQb, pnw, pnb, Yn);

  dim3 gg(M_ / BM, HS_ / BN);
  cast_f32_bf16<<<2048, 256, 0, stream>>>(o_w, wbv, 4194304);
  gemm_nt<false><<<gg, 256, 0, stream>>>(Yn, wbv, out, M_, HS_, HS_);
}